// Round 1
// baseline (552.337 us; speedup 1.0000x reference)
//
#include <hip/hip_runtime.h>
#include <math.h>

#define CC 512
#define K1 25088      // 7*7*512
#define N1 512
#define NE 25690112   // 32*512*8*196 elements per output tensor

typedef unsigned short ushort_t;
typedef __attribute__((ext_vector_type(8))) short bf16x8;
typedef __attribute__((ext_vector_type(4))) float f32x4;
typedef __attribute__((address_space(3))) void* as3_void;
typedef const __attribute__((address_space(1))) void* as1_cvoid;

__device__ __forceinline__ ushort_t f2bf(float f) {
  union { float f; unsigned u; } v; v.f = f;
  unsigned r = v.u + 0x7fffu + ((v.u >> 16) & 1u);
  return (ushort_t)(r >> 16);
}

// ---- W1 (25088 x 512, fp32, row-major [k][n]) -> W1t bf16 [n][k] ----
__global__ void k_w1t(const float* __restrict__ W1, ushort_t* __restrict__ W1t) {
  __shared__ float tile[32][33];
  int k0 = blockIdx.x * 32;
  int n0 = blockIdx.y * 32;
  int tx = threadIdx.x & 31, ty = threadIdx.x >> 5;  // ty 0..7
  for (int r = 0; r < 32; r += 8)
    tile[ty + r][tx] = W1[(k0 + ty + r) * N1 + n0 + tx];
  __syncthreads();
  for (int r = 0; r < 32; r += 8)
    W1t[(size_t)(n0 + ty + r) * K1 + k0 + tx] = f2bf(tile[tx][ty + r]);
}

// ---- pool 14x14 -> 7x7 (exact 2x2 mean) + cast, A[bt][(i*7+j)*512+c] ----
__global__ void k_pool(const float* __restrict__ x, ushort_t* __restrict__ A) {
  int tid = blockIdx.x * 256 + threadIdx.x;   // 32*16*7*512 = 1,835,008
  int c = tid & 511;
  int r = tid >> 9;
  int i = r % 7;
  int r2 = r / 7;
  int t = r2 & 15;
  int b = r2 >> 4;
  const float* src = x + ((size_t)(b * 512 + c) * 16 + t) * 196;
  int bt = b * 16 + t;
  ushort_t* dst = A + (size_t)bt * K1 + i * 7 * 512 + c;
  int h0 = 2 * i * 14;
  for (int j = 0; j < 7; ++j) {
    float2 a0 = *(const float2*)(src + h0 + 2 * j);
    float2 a1 = *(const float2*)(src + h0 + 14 + 2 * j);
    dst[j * 512] = f2bf((a0.x + a0.y + a1.x + a1.y) * 0.25f);
  }
}

// ---- GEMM1: C[512x512] += A[512xK1] * W1t^T, bf16 MFMA, split-K ----
// tiles 128x128, K=512 per block, grid (4,4,49)
__global__ __launch_bounds__(256)
void k_gemm1(const ushort_t* __restrict__ A, const ushort_t* __restrict__ Bt,
             float* __restrict__ C) {
  // conflict-free fragment layout: [k-chunk][row][8 bf16]
  __shared__ __align__(16) short As[4][128][8];
  __shared__ __align__(16) short Bs[4][128][8];
  int row0 = blockIdx.x * 128;
  int col0 = blockIdx.y * 128;
  int k0 = blockIdx.z * 512;
  int lane = threadIdx.x & 63;
  int wave = threadIdx.x >> 6;
  int wm = (wave & 1) * 64;
  int wn = (wave >> 1) * 64;
  f32x4 acc[4][4] = {};

  for (int kk = 0; kk < 512; kk += 32) {
    __syncthreads();
    for (int t = 0; t < 2; ++t) {
      int wt = wave * 2 + t;
      int ch = wt >> 1;            // chunk plane 0..3
      int r0 = (wt & 1) * 64;      // wave-uniform row base
      int rr = r0 + lane;
      const ushort_t* ga = A  + (size_t)(row0 + rr) * K1 + (k0 + kk + ch * 8);
      const ushort_t* gb = Bt + (size_t)(col0 + rr) * K1 + (k0 + kk + ch * 8);
      __builtin_amdgcn_global_load_lds((as1_cvoid)ga, (as3_void)&As[ch][r0][0], 16, 0, 0);
      __builtin_amdgcn_global_load_lds((as1_cvoid)gb, (as3_void)&Bs[ch][r0][0], 16, 0, 0);
    }
    __syncthreads();
    int ml = lane & 15, q = lane >> 4;
    bf16x8 af[4], bfr[4];
    for (int sm = 0; sm < 4; ++sm)
      af[sm] = *(const bf16x8*)&As[q][wm + sm * 16 + ml][0];
    for (int sn = 0; sn < 4; ++sn)
      bfr[sn] = *(const bf16x8*)&Bs[q][wn + sn * 16 + ml][0];
    for (int sm = 0; sm < 4; ++sm)
      for (int sn = 0; sn < 4; ++sn)
        acc[sm][sn] = __builtin_amdgcn_mfma_f32_16x16x32_bf16(af[sm], bfr[sn], acc[sm][sn], 0, 0, 0);
  }
  int ml = lane & 15, q = lane >> 4;
  for (int sm = 0; sm < 4; ++sm)
    for (int sn = 0; sn < 4; ++sn)
      for (int rg = 0; rg < 4; ++rg) {
        int row = row0 + wm + sm * 16 + q * 4 + rg;
        int col = col0 + wn + sn * 16 + ml;
        atomicAdd(&C[row * N1 + col], acc[sm][sn][rg]);
      }
}

// ---- bias + exact GELU ----
__global__ void k_biasgelu(const float* __restrict__ C, const float* __restrict__ b1,
                           float* __restrict__ h) {
  int i = blockIdx.x * 256 + threadIdx.x;  // 262144
  float x = C[i] + b1[i & 511];
  h[i] = 0.5f * x * (1.0f + erff(x * 0.70710678118654752f));
}

// ---- GEMM2: feat[512x64] = h[512x512] @ W2[512x64] + b2 ----
__global__ void k_gemm2(const float* __restrict__ h, const float* __restrict__ W2,
                        const float* __restrict__ b2, float* __restrict__ feat) {
  int bt = blockIdx.x;
  int n = threadIdx.x;  // 64
  __shared__ float hs[512];
  for (int k = threadIdx.x; k < 512; k += 64) hs[k] = h[bt * 512 + k];
  __syncthreads();
  float acc = b2[n];
  for (int k = 0; k < 512; ++k) acc += hs[k] * W2[k * 64 + n];
  feat[bt * 64 + n] = acc;
}

// ---- attention + tanh offsets, one block per batch ----
__global__ void k_attn(const float* __restrict__ feat, const float* __restrict__ Wa,
                       const float* __restrict__ Wd, float* __restrict__ offs) {
  int b = blockIdx.x;
  __shared__ float fl[1024];
  __shared__ float lg[256];
  int tid = threadIdx.x;
  for (int i = tid; i < 1024; i += 256) fl[i] = feat[b * 1024 + i];
  __syncthreads();
  {
    int t = tid >> 4, s = tid & 15;
    float a = 0.f;
    for (int d = 0; d < 64; ++d) a += fl[t * 64 + d] * fl[s * 64 + d];
    lg[tid] = a * (1.0f / 512.0f);
  }
  __syncthreads();
  if (tid < 16) {
    float m = -1e30f;
    for (int s = 0; s < 16; ++s) m = fmaxf(m, lg[tid * 16 + s]);
    float e[16], sum = 0.f;
    for (int s = 0; s < 16; ++s) { e[s] = expf(lg[tid * 16 + s] - m); sum += e[s]; }
    float inv = 1.0f / sum;
    for (int s = 0; s < 16; ++s) lg[tid * 16 + s] = e[s] * inv;
  }
  __syncthreads();
  if (tid < 16) {
    int which = tid >> 3, col = tid & 7;
    const float* W = which ? Wd : Wa;
    float a = 0.f;
    for (int f = 0; f < 256; ++f) a += lg[f] * W[f * 8 + col];
    offs[b * 16 + tid] = tanhf(a) * 2.0f;
  }
}

// ---- temporal bilinear sample: one block per (b,c), slice staged once ----
__global__ void k_sample(const float* __restrict__ x, const float* __restrict__ offs,
                         float* __restrict__ out) {
  int bc = blockIdx.x;        // b*512 + c
  int b = bc >> 9;
  __shared__ float4 xs[16 * 49];   // 16 t-slices x 196 floats
  __shared__ int i0s[16], i1s[16];
  __shared__ float wfr[16];
  int tid = threadIdx.x;
  const float4* src = (const float4*)(x + (size_t)bc * 16 * 196);
  for (int i = tid; i < 784; i += 256) xs[i] = src[i];
  if (tid < 16) {
    int which = tid >> 3, to = tid & 7;
    float idx = (float)(2 * to + which) + offs[b * 16 + tid];
    float p = idx * (16.0f / 15.0f) - 0.5f;
    float fl = floorf(p);
    int i0 = (int)fl;
    wfr[tid] = p - fl;
    i0s[tid] = min(max(i0, 0), 15);
    i1s[tid] = min(max(i0 + 1, 0), 15);
  }
  __syncthreads();
  float4* out4 = (float4*)out;
  for (int oi = tid; oi < 784; oi += 256) {
    int which = oi / 392;
    int rem = oi - which * 392;
    int to = rem / 49;
    int q = rem - to * 49;
    int slot = which * 8 + to;
    float w = wfr[slot];
    float4 g0 = xs[i0s[slot] * 49 + q];
    float4 g1 = xs[i1s[slot] * 49 + q];
    float4 o;
    o.x = g0.x + w * (g1.x - g0.x);
    o.y = g0.y + w * (g1.y - g0.y);
    o.z = g0.z + w * (g1.z - g0.z);
    o.w = g0.w + w * (g1.w - g0.w);
    out4[(size_t)which * (NE / 4) + (size_t)(bc * 8 + to) * 49 + q] = o;
  }
}

extern "C" void kernel_launch(void* const* d_in, const int* in_sizes, int n_in,
                              void* d_out, int out_size, void* d_ws, size_t ws_size,
                              hipStream_t stream) {
  const float* x  = (const float*)d_in[0];
  const float* W1 = (const float*)d_in[1];
  const float* b1 = (const float*)d_in[2];
  const float* W2 = (const float*)d_in[3];
  const float* b2 = (const float*)d_in[4];
  const float* Wa = (const float*)d_in[5];
  const float* Wd = (const float*)d_in[6];
  float* out = (float*)d_out;

  char* w = (char*)d_ws;
  ushort_t* Abf  = (ushort_t*)(w);                 // 25,690,112 B
  ushort_t* W1t  = (ushort_t*)(w + 25690112);      // 25,690,112 B
  float*    C1   = (float*)(w + 51380224);         // 1 MB
  float*    h    = (float*)(w + 52428800);         // 1 MB
  float*    feat = (float*)(w + 53477376);         // 128 KB
  float*    offs = (float*)(w + 53608448);         // 2 KB

  hipMemsetAsync(C1, 0, 1048576, stream);
  k_w1t<<<dim3(784, 16), 256, 0, stream>>>(W1, W1t);
  k_pool<<<7168, 256, 0, stream>>>(x, Abf);
  k_gemm1<<<dim3(4, 4, 49), 256, 0, stream>>>(Abf, W1t, C1);
  k_biasgelu<<<1024, 256, 0, stream>>>(C1, b1, h);
  k_gemm2<<<512, 64, 0, stream>>>(h, W2, b2, feat);
  k_attn<<<32, 256, 0, stream>>>(feat, Wa, Wd, offs);
  k_sample<<<16384, 256, 0, stream>>>(x, offs, out);
}

// Round 2
// 547.403 us; speedup vs baseline: 1.0090x; 1.0090x over previous
//
#include <hip/hip_runtime.h>
#include <math.h>

#define CC 512
#define K1 25088      // 7*7*512
#define N1 512
#define NE 25690112   // 32*512*8*196 elements per output tensor

typedef unsigned short ushort_t;
typedef __attribute__((ext_vector_type(8))) short bf16x8;
typedef __attribute__((ext_vector_type(4))) float f32x4;
typedef __attribute__((address_space(3))) void* as3_void;
typedef const __attribute__((address_space(1))) void* as1_cvoid;

struct us4 { ushort_t a, b, c, d; };

__device__ __forceinline__ ushort_t f2bf(float f) {
  union { float f; unsigned u; } v; v.f = f;
  unsigned r = v.u + 0x7fffu + ((v.u >> 16) & 1u);
  return (ushort_t)(r >> 16);
}

// ---- W1 (25088 x 512 fp32 [k][n]) -> W1t bf16 [n][k], 64x64 tiles ----
// reads: float4 coalesced; writes: ushort4, 128B runs per 16 lanes.
__global__ __launch_bounds__(256)
void k_w1t(const float* __restrict__ W1, ushort_t* __restrict__ W1t) {
  __shared__ float tile[64][65];
  int k0 = blockIdx.x * 64;
  int n0 = blockIdx.y * 64;
  int tid = threadIdx.x;
  int rg = tid >> 4;        // 0..15
  int m  = tid & 15;        // 0..15
  for (int it = 0; it < 4; ++it) {
    int row = rg + it * 16;                       // k within tile
    float4 v = *(const float4*)&W1[(size_t)(k0 + row) * N1 + n0 + m * 4];
    tile[row][m * 4 + 0] = v.x;
    tile[row][m * 4 + 1] = v.y;
    tile[row][m * 4 + 2] = v.z;
    tile[row][m * 4 + 3] = v.w;
  }
  __syncthreads();
  for (int it = 0; it < 4; ++it) {
    int n = rg + it * 16;                         // n within tile
    int kb = m * 4;
    us4 o;
    o.a = f2bf(tile[kb + 0][n]);
    o.b = f2bf(tile[kb + 1][n]);
    o.c = f2bf(tile[kb + 2][n]);
    o.d = f2bf(tile[kb + 3][n]);
    *(us4*)&W1t[(size_t)(n0 + n) * K1 + k0 + kb] = o;
  }
}

// ---- pool 14x14 -> 7x7 + bf16 cast, LDS-staged for coalesced reads ----
// grid: 32b x 16t x 8 c-chunks of 64. A[bt][(i*7+j)*512+c]
__global__ __launch_bounds__(256)
void k_pool(const float* __restrict__ x, ushort_t* __restrict__ A) {
  __shared__ float s[64][197];   // 64 c-slices of 196, pad->5c%32 conflict-free
  int bx = blockIdx.x;
  int cch = bx & 7;
  int t = (bx >> 3) & 15;
  int b = bx >> 7;
  int c0 = cch * 64;
  int tid = threadIdx.x;
  // load 64*49 float4 (784B contiguous per slice)
  for (int idx = tid; idx < 3136; idx += 256) {
    int c = idx / 49;
    int q = idx - c * 49;
    float4 v = *(const float4*)&x[(((size_t)(b * 512 + c0 + c) * 16) + t) * 196 + q * 4];
    s[c][q * 4 + 0] = v.x;
    s[c][q * 4 + 1] = v.y;
    s[c][q * 4 + 2] = v.z;
    s[c][q * 4 + 3] = v.w;
  }
  __syncthreads();
  ushort_t* dst = A + (size_t)(b * 16 + t) * K1 + c0;
  for (int o = tid; o < 3136; o += 256) {
    int ij = o >> 6;          // 0..48
    int c = o & 63;
    int i = ij / 7;
    int j = ij - i * 7;
    int pos = i * 28 + j * 2; // (2i)*14 + 2j
    float v = (s[c][pos] + s[c][pos + 1] + s[c][pos + 14] + s[c][pos + 15]) * 0.25f;
    dst[ij * 512 + c] = f2bf(v);
  }
}

// ---- GEMM1: Cp[z][512][512] = A[512xK1] * W1t^T (bf16 MFMA, split-K 49) ----
__global__ __launch_bounds__(256)
void k_gemm1(const ushort_t* __restrict__ A, const ushort_t* __restrict__ Bt,
             float* __restrict__ Cp) {
  __shared__ __align__(16) short As[4][128][8];
  __shared__ __align__(16) short Bs[4][128][8];
  int row0 = blockIdx.x * 128;
  int col0 = blockIdx.y * 128;
  int k0 = blockIdx.z * 512;
  int lane = threadIdx.x & 63;
  int wave = threadIdx.x >> 6;
  int wm = (wave & 1) * 64;
  int wn = (wave >> 1) * 64;
  f32x4 acc[4][4] = {};

  for (int kk = 0; kk < 512; kk += 32) {
    __syncthreads();
    for (int t = 0; t < 2; ++t) {
      int wt = wave * 2 + t;
      int ch = wt >> 1;            // chunk plane 0..3
      int r0 = (wt & 1) * 64;      // wave-uniform row base
      int rr = r0 + lane;
      const ushort_t* ga = A  + (size_t)(row0 + rr) * K1 + (k0 + kk + ch * 8);
      const ushort_t* gb = Bt + (size_t)(col0 + rr) * K1 + (k0 + kk + ch * 8);
      __builtin_amdgcn_global_load_lds((as1_cvoid)ga, (as3_void)&As[ch][r0][0], 16, 0, 0);
      __builtin_amdgcn_global_load_lds((as1_cvoid)gb, (as3_void)&Bs[ch][r0][0], 16, 0, 0);
    }
    __syncthreads();
    int ml = lane & 15, q = lane >> 4;
    bf16x8 af[4], bfr[4];
    for (int sm = 0; sm < 4; ++sm)
      af[sm] = *(const bf16x8*)&As[q][wm + sm * 16 + ml][0];
    for (int sn = 0; sn < 4; ++sn)
      bfr[sn] = *(const bf16x8*)&Bs[q][wn + sn * 16 + ml][0];
    for (int sm = 0; sm < 4; ++sm)
      for (int sn = 0; sn < 4; ++sn)
        acc[sm][sn] = __builtin_amdgcn_mfma_f32_16x16x32_bf16(af[sm], bfr[sn], acc[sm][sn], 0, 0, 0);
  }
  int ml = lane & 15, q = lane >> 4;
  float* out = Cp + (size_t)blockIdx.z * 262144;
  for (int sm = 0; sm < 4; ++sm)
    for (int sn = 0; sn < 4; ++sn)
      for (int rg = 0; rg < 4; ++rg) {
        int row = row0 + wm + sm * 16 + q * 4 + rg;
        int col = col0 + wn + sn * 16 + ml;
        out[row * N1 + col] = acc[sm][sn][rg];
      }
}

// ---- reduce 49 split-K partials + bias + exact GELU ----
__global__ __launch_bounds__(256)
void k_reduce(const float* __restrict__ Cp, const float* __restrict__ b1,
              float* __restrict__ h) {
  int i = blockIdx.x * 256 + threadIdx.x;   // 262144
  float a = 0.f;
  for (int z = 0; z < 49; ++z) a += Cp[(size_t)z * 262144 + i];
  float xv = a + b1[i & 511];
  h[i] = 0.5f * xv * (1.0f + erff(xv * 0.70710678118654752f));
}

// ---- fused: feat = h @ W2 + b2, attn softmax, tanh offsets. 1 block/batch ----
__global__ __launch_bounds__(256)
void k_head(const float* __restrict__ h, const float* __restrict__ W2,
            const float* __restrict__ b2, const float* __restrict__ Wa,
            const float* __restrict__ Wd, float* __restrict__ offs) {
  int b = blockIdx.x;
  __shared__ float hs[16][512];   // 32KB
  __shared__ float fl[16][65];    // feat, padded
  __shared__ float lg[256];
  int tid = threadIdx.x;
  for (int idx = tid; idx < 8192; idx += 256)
    hs[idx >> 9][idx & 511] = h[(size_t)b * 8192 + idx];
  __syncthreads();
  {
    int n = tid & 63;
    int tg = tid >> 6;            // t = tg, tg+4, tg+8, tg+12
    float acc0 = b2[n], acc1 = acc0, acc2 = acc0, acc3 = acc0;
    for (int k = 0; k < 512; ++k) {
      float w = W2[k * 64 + n];
      acc0 += hs[tg][k] * w;
      acc1 += hs[tg + 4][k] * w;
      acc2 += hs[tg + 8][k] * w;
      acc3 += hs[tg + 12][k] * w;
    }
    fl[tg][n] = acc0;
    fl[tg + 4][n] = acc1;
    fl[tg + 8][n] = acc2;
    fl[tg + 12][n] = acc3;
  }
  __syncthreads();
  {
    int t = tid >> 4, s = tid & 15;
    float a = 0.f;
    for (int d = 0; d < 64; ++d) a += fl[t][d] * fl[s][d];
    lg[tid] = a * (1.0f / 512.0f);
  }
  __syncthreads();
  if (tid < 16) {
    float m = -1e30f;
    for (int s = 0; s < 16; ++s) m = fmaxf(m, lg[tid * 16 + s]);
    float e[16], sum = 0.f;
    for (int s = 0; s < 16; ++s) { e[s] = expf(lg[tid * 16 + s] - m); sum += e[s]; }
    float inv = 1.0f / sum;
    for (int s = 0; s < 16; ++s) lg[tid * 16 + s] = e[s] * inv;
  }
  __syncthreads();
  if (tid < 16) {
    int which = tid >> 3, col = tid & 7;
    const float* W = which ? Wd : Wa;
    float a = 0.f;
    for (int f = 0; f < 256; ++f) a += lg[f] * W[f * 8 + col];
    offs[b * 16 + tid] = tanhf(a) * 2.0f;
  }
}

// ---- temporal bilinear sample: one block per (b,c), slice staged once ----
__global__ __launch_bounds__(256)
void k_sample(const float* __restrict__ x, const float* __restrict__ offs,
              float* __restrict__ out) {
  int bc = blockIdx.x;        // b*512 + c
  int b = bc >> 9;
  __shared__ float4 xs[16 * 49];   // 16 t-slices x 196 floats
  __shared__ int i0s[16], i1s[16];
  __shared__ float wfr[16];
  int tid = threadIdx.x;
  const float4* src = (const float4*)(x + (size_t)bc * 16 * 196);
  for (int i = tid; i < 784; i += 256) xs[i] = src[i];
  if (tid < 16) {
    int which = tid >> 3, to = tid & 7;
    float idx = (float)(2 * to + which) + offs[b * 16 + tid];
    float p = idx * (16.0f / 15.0f) - 0.5f;
    float fl = floorf(p);
    int i0 = (int)fl;
    wfr[tid] = p - fl;
    i0s[tid] = min(max(i0, 0), 15);
    i1s[tid] = min(max(i0 + 1, 0), 15);
  }
  __syncthreads();
  float4* out4 = (float4*)out;
  for (int oi = tid; oi < 784; oi += 256) {
    int which = oi / 392;
    int rem = oi - which * 392;
    int to = rem / 49;
    int q = rem - to * 49;
    int slot = which * 8 + to;
    float w = wfr[slot];
    float4 g0 = xs[i0s[slot] * 49 + q];
    float4 g1 = xs[i1s[slot] * 49 + q];
    float4 o;
    o.x = g0.x + w * (g1.x - g0.x);
    o.y = g0.y + w * (g1.y - g0.y);
    o.z = g0.z + w * (g1.z - g0.z);
    o.w = g0.w + w * (g1.w - g0.w);
    out4[(size_t)which * (NE / 4) + (size_t)(bc * 8 + to) * 49 + q] = o;
  }
}

extern "C" void kernel_launch(void* const* d_in, const int* in_sizes, int n_in,
                              void* d_out, int out_size, void* d_ws, size_t ws_size,
                              hipStream_t stream) {
  const float* x  = (const float*)d_in[0];
  const float* W1 = (const float*)d_in[1];
  const float* b1 = (const float*)d_in[2];
  const float* W2 = (const float*)d_in[3];
  const float* b2 = (const float*)d_in[4];
  const float* Wa = (const float*)d_in[5];
  const float* Wd = (const float*)d_in[6];
  float* out = (float*)d_out;

  char* w = (char*)d_ws;
  ushort_t* Abf  = (ushort_t*)(w);                 // 25,690,112 B
  ushort_t* W1t  = (ushort_t*)(w + 25690112);      // 25,690,112 B
  float*    Cp   = (float*)(w + 51380224);         // 49 MB partials
  float*    h    = (float*)(w + 51380224 + 51380224);  // 1 MB
  float*    feat_offs = (float*)(w + 51380224 + 51380224 + 1048576);

  float* offs = feat_offs;                          // 2 KB

  k_w1t<<<dim3(392, 8), 256, 0, stream>>>(W1, W1t);
  k_pool<<<4096, 256, 0, stream>>>(x, Abf);
  k_gemm1<<<dim3(4, 4, 49), 256, 0, stream>>>(Abf, W1t, Cp);
  k_reduce<<<1024, 256, 0, stream>>>(Cp, b1, h);
  k_head<<<32, 256, 0, stream>>>(h, W2, b2, Wa, Wd, offs);
  k_sample<<<16384, 256, 0, stream>>>(x, offs, out);
}